// Round 4
// baseline (40.445 us; speedup 1.0000x reference)
//
#include <hip/hip_runtime.h>

#define NFEAT 2000
#define NMID  1998
#define BATCH 4096
#define PI_2  1.57079632679489662f
#define RPK   192    // cores repacked for the fast path (early exit expected ~step 40)

// ---- explicit-pattern DPP lane-xor within each 16-lane row ----
// quad_perm and mirrors have unambiguous lane maps (no shl/shr/ror direction risk).
template<int CTRL>
__device__ __forceinline__ float dppf(float x) {
    int i = __float_as_int(x);
    return __int_as_float(__builtin_amdgcn_update_dpp(i, i, CTRL, 0xF, 0xF, false));
}
__device__ __forceinline__ float xor1f(float x){ return dppf<0xB1>(x); }               // quad_perm(1,0,3,2)
__device__ __forceinline__ float xor2f(float x){ return dppf<0x4E>(x); }               // quad_perm(2,3,0,1)
__device__ __forceinline__ float xor4f(float x){ return dppf<0x1B>(dppf<0x141>(x)); }  // (l^7) then (l^3) = l^4
__device__ __forceinline__ float xor8f(float x){ return dppf<0x141>(dppf<0x140>(x)); } // (l^15) then (l^7) = l^8

// ---- repack: ws[m][l][k] = cm[m][l ^ g(k>>1)][k&1][l],  g(j) = j ^ (j>>1) ----
// Lane l's 32 needed matrix values per step become one contiguous 128B run.
__global__ __launch_bounds__(64, 1)
void repack_kernel(const float* __restrict__ cm, float* __restrict__ ws)
{
    __shared__ float Mv[512];
    const int m = blockIdx.x;
    const int t = threadIdx.x;
    const float4* src = (const float4*)(cm + (size_t)m * 512);
    ((float4*)Mv)[t]      = src[t];
    ((float4*)Mv)[t + 64] = src[t + 64];
    __syncthreads();
    const int l = t >> 2;     // 0..15
    const int q = t & 3;      // owns k = q*8 .. q*8+7
    float o[8];
    #pragma unroll
    for (int kk = 0; kk < 8; ++kk) {
        const int k  = q * 8 + kk;
        const int j  = k >> 1;
        const int gg = j ^ (j >> 1);
        o[kk] = Mv[((l ^ gg) << 5) + ((k & 1) << 4) + l];
    }
    float4* dst = (float4*)(ws + (size_t)m * 512 + l * 32 + q * 8);
    dst[0] = make_float4(o[0], o[1], o[2], o[3]);
    dst[1] = make_float4(o[4], o[5], o[6], o[7]);
}

// One chain step from repacked data: v_new[l] = sum_d v[d]*(c*M[d][0][l]+s*M[d][1][l]).
// vx walks d = l ^ g(j) in Gray order; one single-dpp xor between most iterations.
__device__ __forceinline__ void step(float& v, const float4 (&m4)[8], float xv)
{
    const float th = xv * PI_2;
    const float c = __cosf(th), s = __sinf(th);
    float vx = v;
    float acc;
    acc =      vx * fmaf(s, m4[0].y, c * m4[0].x);        // j=0  g=0
    vx = xor1f(vx);
    acc = fmaf(vx, fmaf(s, m4[0].w, c * m4[0].z), acc);   // j=1  g=1
    vx = xor2f(vx);
    acc = fmaf(vx, fmaf(s, m4[1].y, c * m4[1].x), acc);   // j=2  g=3
    vx = xor1f(vx);
    acc = fmaf(vx, fmaf(s, m4[1].w, c * m4[1].z), acc);   // j=3  g=2
    vx = xor4f(vx);
    acc = fmaf(vx, fmaf(s, m4[2].y, c * m4[2].x), acc);   // j=4  g=6
    vx = xor1f(vx);
    acc = fmaf(vx, fmaf(s, m4[2].w, c * m4[2].z), acc);   // j=5  g=7
    vx = xor2f(vx);
    acc = fmaf(vx, fmaf(s, m4[3].y, c * m4[3].x), acc);   // j=6  g=5
    vx = xor1f(vx);
    acc = fmaf(vx, fmaf(s, m4[3].w, c * m4[3].z), acc);   // j=7  g=4
    vx = xor8f(vx);
    acc = fmaf(vx, fmaf(s, m4[4].y, c * m4[4].x), acc);   // j=8  g=12
    vx = xor1f(vx);
    acc = fmaf(vx, fmaf(s, m4[4].w, c * m4[4].z), acc);   // j=9  g=13
    vx = xor2f(vx);
    acc = fmaf(vx, fmaf(s, m4[5].y, c * m4[5].x), acc);   // j=10 g=15
    vx = xor1f(vx);
    acc = fmaf(vx, fmaf(s, m4[5].w, c * m4[5].z), acc);   // j=11 g=14
    vx = xor4f(vx);
    acc = fmaf(vx, fmaf(s, m4[6].y, c * m4[6].x), acc);   // j=12 g=10
    vx = xor1f(vx);
    acc = fmaf(vx, fmaf(s, m4[6].w, c * m4[6].z), acc);   // j=13 g=11
    vx = xor2f(vx);
    acc = fmaf(vx, fmaf(s, m4[7].y, c * m4[7].x), acc);   // j=14 g=9
    vx = xor1f(vx);
    acc = fmaf(vx, fmaf(s, m4[7].w, c * m4[7].z), acc);   // j=15 g=8
    v = acc;
}

// Same step from the ORIGINAL cm layout (gathered dword loads). Fallback only.
__device__ __forceinline__ void step_raw(float& v, const float* __restrict__ M,
                                         int l, float xv)
{
    const float th = xv * PI_2;
    const float c = __cosf(th), s = __sinf(th);
    float vx = v;
    float acc = 0.f;
    #pragma unroll
    for (int j = 0; j < 16; ++j) {
        const int gg = j ^ (j >> 1);
        const float* row = M + ((l ^ gg) << 5) + l;
        acc = fmaf(vx, fmaf(s, row[16], c * row[0]), acc);
        if (j < 15) {
            const int tm = gg ^ ((j + 1) ^ ((j + 1) >> 1));
            vx = (tm == 1) ? xor1f(vx) : (tm == 2) ? xor2f(vx)
               : (tm == 4) ? xor4f(vx) : xor8f(vx);
        }
    }
    v = acc;
}

// ---- main: one 16-lane group per sample, left chain only, per-step exit vote ----
__global__ __launch_bounds__(256, 1)
void mps_diag_kernel(const float* __restrict__ x,  const float* __restrict__ cf,
                     const float* __restrict__ cm, const float* __restrict__ cl,
                     const float* __restrict__ ws, float* __restrict__ out)
{
    const int tid = threadIdx.x;
    const int l   = tid & 15;
    const int b   = blockIdx.x * 16 + (tid >> 4);
    const size_t xrow = (size_t)b * NFEAT;

    // v0 from core_first and feature 0
    float v;
    {
        const float th = x[xrow] * PI_2;
        v = fmaf(__sinf(th), cf[16 + l], __cosf(th) * cf[l]);
    }

    const float4* wsl = (const float4*)ws + l * 8;   // lane's 128B run per core

    float4 A[8], B[8];
    #pragma unroll
    for (int k = 0; k < 8; ++k) A[k] = wsl[k];       // core m=0
    float xa = x[xrow + 1];
    float xb = x[xrow + 2];

    int  m = 0;
    bool dead = false;
    for (; m + 1 < RPK; m += 2) {
        #pragma unroll
        for (int k = 0; k < 8; ++k) B[k] = wsl[(m + 1) * 128 + k];
        const float xn0 = x[xrow + m + 3];
        step(v, A, xa);
        if (__all(v == 0.0f)) { dead = true; break; }
        #pragma unroll
        for (int k = 0; k < 8; ++k) A[k] = wsl[(m + 2) * 128 + k];
        const float xn1 = x[xrow + m + 4];
        step(v, B, xb);
        if (__all(v == 0.0f)) { dead = true; break; }
        xa = xn0; xb = xn1;
    }

    if (!dead) {
        // fallback: finish the chain from the original layout (exact; normally dead)
        for (; m < NMID; ++m) {
            const float xv = x[xrow + m + 1];
            step_raw(v, cm + (size_t)m * 512, l, xv);
            if (__all(v == 0.0f)) break;
        }
    }

    // epilogue: out[b] = sum_d v[d] * (c*cl[d][0] + s*cl[d][1])  (exact 0 if v==0)
    {
        const float th = x[xrow + NFEAT - 1] * PI_2;
        float p = v * fmaf(__sinf(th), cl[2 * l + 1], __cosf(th) * cl[2 * l]);
        p += xor1f(p);
        p += xor2f(p);
        p += xor4f(p);
        p += xor8f(p);
        if (l == 0) out[b] = p;
    }
}

extern "C" void kernel_launch(void* const* d_in, const int* in_sizes, int n_in,
                              void* d_out, int out_size, void* d_ws, size_t ws_size,
                              hipStream_t stream) {
    const float* x  = (const float*)d_in[0];
    const float* cf = (const float*)d_in[1];
    const float* cm = (const float*)d_in[2];
    const float* cl = (const float*)d_in[3];
    float* ws  = (float*)d_ws;      // needs RPK*512*4 = 393 KB
    float* out = (float*)d_out;
    hipLaunchKernelGGL(repack_kernel, dim3(RPK), dim3(64), 0, stream, cm, ws);
    hipLaunchKernelGGL(mps_diag_kernel, dim3(BATCH / 16), dim3(256), 0, stream,
                       x, cf, cm, cl, ws, out);
}

// Round 5
// 15.813 us; speedup vs baseline: 2.5577x; 2.5577x over previous
//
#include <hip/hip_runtime.h>

#define NFEAT 2000
#define NMID  1998
#define BATCH 4096
#define PI_2  1.57079632679489662f

// Column-decomposition MPS chain, left-to-right only.
//   lane l of a 16-lane group owns component l of the bond vector.
//   v'[l] = sum_d v[d] * (c*M[d][0][l] + s*M[d][1][l])
// For fixed (d,p) the 16 lanes read 64 contiguous bytes of cm -> coalesced,
// no repacking needed. Full-v redistribution goes through a tiny LDS buffer;
// each group lives inside one wave, so DS ops are wave-ordered (no barriers).
//
// EARLY EXIT: cores are 0.01-scale, so ||v|| contracts ~25x per step and v
// underflows to exact fp32 zero after ~35 steps. Zero is absorbing (0-vector
// in, 0-vector out, exactly), so once the wave's 4 samples are all-zero the
// remaining chain is provably a no-op. Vote every 2 steps (still exact).

#define REFILL(A, mm) do {                                                  \
    const float* _p = cm + (size_t)(mm) * 512 + l;                          \
    _Pragma("unroll")                                                       \
    for (int _d = 0; _d < 16; ++_d) {                                       \
        A[_d]      = _p[_d * 32];                                           \
        A[16 + _d] = _p[_d * 32 + 16];                                      \
    } } while (0)

#define DOT16(R, A, OFF) do {                                               \
    R = 0.f;                                                                \
    _Pragma("unroll")                                                       \
    for (int _j = 0; _j < 4; ++_j) {                                        \
        R = fmaf(W[_j].x, A[OFF + 4 * _j + 0], R);                          \
        R = fmaf(W[_j].y, A[OFF + 4 * _j + 1], R);                          \
        R = fmaf(W[_j].z, A[OFF + 4 * _j + 2], R);                          \
        R = fmaf(W[_j].w, A[OFF + 4 * _j + 3], R);                          \
    } } while (0)

#define STEP(A, XV) do {                                                    \
    const float _th = (XV) * PI_2;                                          \
    const float _c = __cosf(_th), _s = __sinf(_th);                         \
    float _dA, _dB;                                                         \
    DOT16(_dA, A, 0);                                                       \
    DOT16(_dB, A, 16);                                                      \
    v = fmaf(_c, _dA, _s * _dB);                                            \
    } while (0)

#define EXCH() do {                                                         \
    vx[g][l] = v;                                                           \
    W[0] = *(const float4*)&vx[g][0];                                       \
    W[1] = *(const float4*)&vx[g][4];                                       \
    W[2] = *(const float4*)&vx[g][8];                                       \
    W[3] = *(const float4*)&vx[g][12];                                      \
    } while (0)

__global__ __launch_bounds__(256, 1)
void mps_col_kernel(const float* __restrict__ x,  const float* __restrict__ cf,
                    const float* __restrict__ cm, const float* __restrict__ cl,
                    float* __restrict__ out)
{
    __shared__ float vx[16][20];   // padded: group exchange buffer, 1.25 KB

    const int tid = threadIdx.x;
    const int g   = tid >> 4;      // sample slot 0..15
    const int l   = tid & 15;      // bond lane 0..15
    const int b   = blockIdx.x * 16 + g;
    const size_t xrow = (size_t)b * NFEAT;

    // ---- v0 from core_first, feature 0 ----
    float v;
    {
        const float th = x[xrow] * PI_2;
        v = fmaf(__sinf(th), cf[16 + l], __cosf(th) * cf[l]);
    }

    float4 W[4];
    EXCH();                        // distribute v0 to the group

    // ---- pipeline prologue: columns for steps 0 and 1, features 1 and 2 ----
    float a0[32], a1[32];
    REFILL(a0, 0);
    REFILL(a1, 1);
    float xa = x[xrow + 1];
    float xb = x[xrow + 2];

    bool dead = false;
    for (int m = 0; m < NMID - 2; m += 2) {
        STEP(a0, xa);              // step m
        EXCH();
        REFILL(a0, m + 2);         // refill one full step ahead of use
        xa = x[xrow + m + 3];
        STEP(a1, xb);              // step m+1
        if (__all(v == 0.0f)) { dead = true; break; }
        EXCH();
        REFILL(a1, m + 3);
        xb = x[xrow + m + 4];
    }
    if (!dead) {                   // tail: steps 1996, 1997 (already in a0/a1)
        STEP(a0, xa);
        EXCH();
        STEP(a1, xb);
    }

    // ---- epilogue: out[b] = sum_l v[l] * (c*cl[l][0] + s*cl[l][1]) ----
    {
        const float th = x[xrow + NFEAT - 1] * PI_2;
        float p = v * fmaf(__sinf(th), cl[2 * l + 1], __cosf(th) * cl[2 * l]);
        p += __shfl_xor(p, 1);
        p += __shfl_xor(p, 2);
        p += __shfl_xor(p, 4);
        p += __shfl_xor(p, 8);
        if (l == 0) out[b] = p;
    }
}

extern "C" void kernel_launch(void* const* d_in, const int* in_sizes, int n_in,
                              void* d_out, int out_size, void* d_ws, size_t ws_size,
                              hipStream_t stream) {
    const float* x  = (const float*)d_in[0];
    const float* cf = (const float*)d_in[1];
    const float* cm = (const float*)d_in[2];
    const float* cl = (const float*)d_in[3];
    float* out = (float*)d_out;
    hipLaunchKernelGGL(mps_col_kernel, dim3(BATCH / 16), dim3(256), 0, stream,
                       x, cf, cm, cl, out);
}